// Round 7
// baseline (355.283 us; speedup 1.0000x reference)
//
#include <hip/hip_runtime.h>
#include <hip/hip_cooperative_groups.h>
#include <math.h>

namespace cg = cooperative_groups;

// Problem constants (B=1)
#define S 2048
#define DM 512
#define WIN 64
#define ATTN_SCALE 0.17677669529663687f   // 1/sqrt(32)
#define GRID 512
#define NTHR (GRID * 256)                  // 131072 threads

typedef __attribute__((ext_vector_type(8))) short short8;   // 8 x bf16
typedef __attribute__((ext_vector_type(4))) float floatx4;  // MFMA acc

__device__ __forceinline__ unsigned short f2bf(float f) {   // RNE (R3-verified)
  unsigned int u = __float_as_uint(f);
  return (unsigned short)((u + 0x7FFFu + ((u >> 16) & 1u)) >> 16);
}
// Pack two fp32 -> (bf1<<16)|bf0, round-half-up (R6-verified numerics).
__device__ __forceinline__ unsigned int pack_bf16_rh(float f0, float f1) {
  unsigned int u0 = __float_as_uint(f0) + 0x8000u;
  unsigned int u1 = __float_as_uint(f1) + 0x8000u;
  return __builtin_amdgcn_perm(u1, u0, 0x07060302u);
}

// ---------------------------------------------------------------------------
// Single cooperative kernel, 4 phases separated by grid.sync():
//   P0 convert fp32->bf16 (x + 4 W planes)
//   P1 QKV GEMM  {q|k|v} = x*W_z^T  (bf16 MFMA, bf16 out), 768 64x64 tiles
//   P2 sliding-window per-channel softmax (bf16 in/out)
//   P3 out projection  out = attn*Wo^T (fp32 out), 256 tiles
// GEMM machinery is the R3-verified 64x64/BK=64 tile with 16B-granule XOR
// swizzle (slot g^(r&7)); attn is the R6-verified 2-channel/thread loop.
// __launch_bounds__(256,2): 2 blocks/CU guaranteed -> 512 blocks co-resident.
// ---------------------------------------------------------------------------
__global__ __launch_bounds__(256, 2) void fused_swa(
    const float* __restrict__ x,  const float* __restrict__ Wq,
    const float* __restrict__ Wk, const float* __restrict__ Wv,
    const float* __restrict__ Wo, float* __restrict__ out,
    unsigned short* __restrict__ xbf,    // 1M bf16
    unsigned short* __restrict__ wbf,    // 4 x 256K bf16
    unsigned short* __restrict__ qkvb,   // 3 x 1M bf16
    unsigned short* __restrict__ attnb)  // 1M bf16
{
  __shared__ unsigned short As[64 * 64];   // 8 KB
  __shared__ unsigned short Bs[64 * 64];   // 8 KB
  cg::grid_group grid = cg::this_grid();

  const int tid  = threadIdx.x;
  const int bid  = blockIdx.x;
  const int gtid = bid * 256 + tid;

  // ---------------- P0: fp32 -> bf16 (2M elems = 524288 float4) ------------
  for (int t = gtid; t < 524288; t += NTHR) {
    size_t i4 = (size_t)t * 4;
    const float* src; unsigned short* dst; size_t off;
    if (i4 < (size_t)S * DM) {
      src = x; dst = xbf; off = i4;
    } else {
      size_t r = i4 - (size_t)S * DM;
      int wsel = (int)(r >> 18);
      src = wsel == 0 ? Wq : wsel == 1 ? Wk : wsel == 2 ? Wv : Wo;
      dst = wbf + ((size_t)wsel << 18);
      off = r & 262143;
    }
    float4 f = *(const float4*)(src + off);
    ushort4 o;
    o.x = f2bf(f.x); o.y = f2bf(f.y); o.z = f2bf(f.z); o.w = f2bf(f.w);
    *(ushort4*)(dst + off) = o;
  }
  grid.sync();

  // GEMM lane decomposition (shared by P1/P3)
  const int lane = tid & 63;
  const int w    = tid >> 6;
  const int wr   = w >> 1;
  const int wc   = w & 1;
  const int quad = lane >> 4;
  const int lc   = lane & 15;
  const int trow = tid >> 3;                 // 0..31
  const int tg   = tid & 7;                  // 16B granule 0..7
  const int tslot = (tg ^ (trow & 7)) * 8;   // swizzled elem offset

  // ---------------- P1: QKV GEMM, 768 tiles grid-strided -------------------
  for (int t = bid; t < 768; t += GRID) {
    const int z    = t >> 8;                 // plane 0..2
    const int tt   = t & 255;
    const int row0 = (tt >> 3) * 64;
    const int col0 = (tt & 7) * 64;
    const unsigned short* Bp = wbf + ((size_t)z << 18);
    unsigned short* C = qkvb + (size_t)z * ((size_t)S * DM);

    floatx4 acc[2][2] = {};
    for (int k0 = 0; k0 < DM; k0 += 64) {
      uint4 ua[2], ub[2];
#pragma unroll
      for (int u = 0; u < 2; ++u) {
        ua[u] = *(const uint4*)&xbf[(size_t)(row0 + u * 32 + trow) * DM + k0 + tg * 8];
        ub[u] = *(const uint4*)&Bp[(size_t)(col0 + u * 32 + trow) * DM + k0 + tg * 8];
      }
      __syncthreads();   // prior LDS reads complete
#pragma unroll
      for (int u = 0; u < 2; ++u) {
        *(uint4*)&As[(u * 32 + trow) * 64 + tslot] = ua[u];
        *(uint4*)&Bs[(u * 32 + trow) * 64 + tslot] = ub[u];
      }
      __syncthreads();

#pragma unroll
      for (int s = 0; s < 2; ++s) {
        const int gk = s * 4 + quad;
        short8 aF[2], bF[2];
#pragma unroll
        for (int i = 0; i < 2; ++i) {
          const int m = wr * 32 + i * 16 + lc;
          aF[i] = *(const short8*)&As[m * 64 + (gk ^ (m & 7)) * 8];
        }
#pragma unroll
        for (int j = 0; j < 2; ++j) {
          const int n = wc * 32 + j * 16 + lc;
          bF[j] = *(const short8*)&Bs[n * 64 + (gk ^ (n & 7)) * 8];
        }
#pragma unroll
        for (int i = 0; i < 2; ++i)
#pragma unroll
          for (int j = 0; j < 2; ++j)
            acc[i][j] = __builtin_amdgcn_mfma_f32_16x16x32_bf16(
                aF[i], bF[j], acc[i][j], 0, 0, 0);
      }
    }
    // C/D layout: col = lane&15, row = quad*4 + reg  [m89/m91]
#pragma unroll
    for (int i = 0; i < 2; ++i)
#pragma unroll
      for (int j = 0; j < 2; ++j) {
        const int col = col0 + wc * 32 + j * 16 + lc;
#pragma unroll
        for (int r = 0; r < 4; ++r) {
          const int row = row0 + wr * 32 + i * 16 + quad * 4 + r;
          C[(size_t)row * DM + col] = f2bf(acc[i][j][r]);
        }
      }
  }
  grid.sync();

  // ---------------- P2: sliding-window per-channel softmax -----------------
  {
    const unsigned short* q = qkvb;
    const unsigned short* k = qkvb + (size_t)S * DM;
    const unsigned short* v = qkvb + 2 * (size_t)S * DM;
    for (int u = gtid; u < S * DM / 2; u += NTHR) {
      const int i  = u >> 8;             // row (block-uniform per iteration)
      const int c2 = (u & 255) * 2;      // channel pair

      const unsigned int qp = *(const unsigned int*)&q[(size_t)i * DM + c2];
      const float q0 = __uint_as_float(qp << 16) * ATTN_SCALE;
      const float q1 = __uint_as_float(qp & 0xffff0000u) * ATTN_SCALE;

      float l0 = 0.f, l1 = 0.f, a0 = 0.f, a1 = 0.f;
      const int j0 = i > (WIN - 1) ? i - (WIN - 1) : 0;
      for (int j = j0; j <= i; ++j) {
        const unsigned int kp = *(const unsigned int*)&k[(size_t)j * DM + c2];
        const unsigned int vp = *(const unsigned int*)&v[(size_t)j * DM + c2];
        const float p0 = __expf(q0 * __uint_as_float(kp << 16));
        const float p1 = __expf(q1 * __uint_as_float(kp & 0xffff0000u));
        l0 += p0; l1 += p1;
        a0 = fmaf(p0, __uint_as_float(vp << 16), a0);
        a1 = fmaf(p1, __uint_as_float(vp & 0xffff0000u), a1);
      }
      *(unsigned int*)&attnb[(size_t)i * DM + c2] = pack_bf16_rh(a0 / l0, a1 / l1);
    }
  }
  grid.sync();

  // ---------------- P3: out projection, 256 tiles (blocks 0..255) ----------
  if (bid < 256) {
    const int row0 = (bid >> 3) * 64;
    const int col0 = (bid & 7) * 64;
    const unsigned short* Bp = wbf + ((size_t)3 << 18);

    floatx4 acc[2][2] = {};
    for (int k0 = 0; k0 < DM; k0 += 64) {
      uint4 ua[2], ub[2];
#pragma unroll
      for (int u = 0; u < 2; ++u) {
        ua[u] = *(const uint4*)&attnb[(size_t)(row0 + u * 32 + trow) * DM + k0 + tg * 8];
        ub[u] = *(const uint4*)&Bp[(size_t)(col0 + u * 32 + trow) * DM + k0 + tg * 8];
      }
      __syncthreads();
#pragma unroll
      for (int u = 0; u < 2; ++u) {
        *(uint4*)&As[(u * 32 + trow) * 64 + tslot] = ua[u];
        *(uint4*)&Bs[(u * 32 + trow) * 64 + tslot] = ub[u];
      }
      __syncthreads();

#pragma unroll
      for (int s = 0; s < 2; ++s) {
        const int gk = s * 4 + quad;
        short8 aF[2], bF[2];
#pragma unroll
        for (int i = 0; i < 2; ++i) {
          const int m = wr * 32 + i * 16 + lc;
          aF[i] = *(const short8*)&As[m * 64 + (gk ^ (m & 7)) * 8];
        }
#pragma unroll
        for (int j = 0; j < 2; ++j) {
          const int n = wc * 32 + j * 16 + lc;
          bF[j] = *(const short8*)&Bs[n * 64 + (gk ^ (n & 7)) * 8];
        }
#pragma unroll
        for (int i = 0; i < 2; ++i)
#pragma unroll
          for (int j = 0; j < 2; ++j)
            acc[i][j] = __builtin_amdgcn_mfma_f32_16x16x32_bf16(
                aF[i], bF[j], acc[i][j], 0, 0, 0);
      }
    }
#pragma unroll
    for (int i = 0; i < 2; ++i)
#pragma unroll
      for (int j = 0; j < 2; ++j) {
        const int col = col0 + wc * 32 + j * 16 + lc;
#pragma unroll
        for (int r = 0; r < 4; ++r) {
          const int row = row0 + wr * 32 + i * 16 + quad * 4 + r;
          out[(size_t)row * DM + col] = acc[i][j][r];
        }
      }
  }
}

// ---------------------------------------------------------------------------
// Launch: ONE cooperative dispatch.
// ---------------------------------------------------------------------------
extern "C" void kernel_launch(void* const* d_in, const int* in_sizes, int n_in,
                              void* d_out, int out_size, void* d_ws, size_t ws_size,
                              hipStream_t stream) {
  const float* x  = (const float*)d_in[0];
  const float* Wq = (const float*)d_in[1];
  const float* Wk = (const float*)d_in[2];
  const float* Wv = (const float*)d_in[3];
  const float* Wo = (const float*)d_in[4];
  float* out = (float*)d_out;

  // ws: xbf 2MB | wbf 2MB | qkvb 6MB | attnb 2MB  (12 MB total)
  unsigned short* xbf   = (unsigned short*)d_ws;
  unsigned short* wbf   = xbf + (size_t)S * DM;
  unsigned short* qkvb  = wbf + 4 * (size_t)DM * DM;
  unsigned short* attnb = qkvb + 3 * (size_t)S * DM;

  void* args[] = {(void*)&x, (void*)&Wq, (void*)&Wk, (void*)&Wv, (void*)&Wo,
                  (void*)&out, (void*)&xbf, (void*)&wbf, (void*)&qkvb,
                  (void*)&attnb};
  hipLaunchCooperativeKernel((const void*)fused_swa, dim3(GRID), dim3(256),
                             args, 0, stream);
}

// Round 8
// 145.441 us; speedup vs baseline: 2.4428x; 2.4428x over previous
//
#include <hip/hip_runtime.h>
#include <math.h>

// Problem constants (B=1)
#define S 2048
#define DM 512
#define WIN 64
#define ATTN_SCALE 0.17677669529663687f   // 1/sqrt(32)

typedef __attribute__((ext_vector_type(8))) short short8;   // 8 x bf16
typedef __attribute__((ext_vector_type(4))) float floatx4;  // MFMA acc

__device__ __forceinline__ unsigned short f2bf(float f) {   // RNE
  unsigned int u = __float_as_uint(f);
  return (unsigned short)((u + 0x7FFFu + ((u >> 16) & 1u)) >> 16);
}
// Pack two fp32 -> (bf1<<16)|bf0, round-half-up (R6-verified numerics).
__device__ __forceinline__ unsigned int pack_bf16_rh(float f0, float f1) {
  unsigned int u0 = __float_as_uint(f0) + 0x8000u;
  unsigned int u1 = __float_as_uint(f1) + 0x8000u;
  return __builtin_amdgcn_perm(u1, u0, 0x07060302u);
}
__device__ __forceinline__ void unpack2(unsigned int p, float& f0, float& f1) {
  f0 = __uint_as_float(p << 16);
  f1 = __uint_as_float(p & 0xffff0000u);
}

// ---------------------------------------------------------------------------
// Convert x (S*DM floats) and Wq|Wk|Wv|Wo (4 * DM*DM) to bf16. (R3-verified)
// ---------------------------------------------------------------------------
__global__ __launch_bounds__(256) void convert_bf16(
    const float* __restrict__ x, const float* __restrict__ Wq,
    const float* __restrict__ Wk, const float* __restrict__ Wv,
    const float* __restrict__ Wo,
    unsigned short* __restrict__ xbf, unsigned short* __restrict__ wbf) {
  size_t i4 = ((size_t)blockIdx.x * 256 + threadIdx.x) * 4;
  const float* src; unsigned short* dst; size_t off;
  const size_t NX = (size_t)S * DM;           // 1,048,576
  if (i4 < NX) {
    src = x; dst = xbf; off = i4;
  } else {
    size_t r = i4 - NX;
    int wsel = (int)(r >> 18);                // / (512*512)
    src = wsel == 0 ? Wq : wsel == 1 ? Wk : wsel == 2 ? Wv : Wo;
    dst = wbf + ((size_t)wsel << 18);
    off = r & 262143;
  }
  float4 f = *(const float4*)(src + off);
  ushort4 o;
  o.x = f2bf(f.x); o.y = f2bf(f.y); o.z = f2bf(f.z); o.w = f2bf(f.w);
  *(ushort4*)(dst + off) = o;
}

// ---------------------------------------------------------------------------
// QKV GEMM (R3-verified tile): {q|k|v}[M,N] bf16 = x[M,K]bf16 * W_z[N,K]^T.
// 64x64 tile, BK=64, 4 waves (2x2), 2x2 of mfma_f32_16x16x32_bf16.
// LDS 16B-granule XOR swizzle: slot g^(r&7). Grid 8x32x3 = 768 blocks.
// ---------------------------------------------------------------------------
__global__ __launch_bounds__(256) void gemm_qkv(
    const unsigned short* __restrict__ Abf,
    const unsigned short* __restrict__ wbf,
    unsigned short* __restrict__ Cb) {
  __shared__ unsigned short As[64 * 64];
  __shared__ unsigned short Bs[64 * 64];

  const int z = blockIdx.z;
  const unsigned short* Bp = wbf + ((size_t)z << 18);
  unsigned short* C = Cb + (size_t)z * ((size_t)S * DM);

  const int row0 = blockIdx.y * 64;
  const int col0 = blockIdx.x * 64;
  const int tid  = threadIdx.x;
  const int lane = tid & 63;
  const int w    = tid >> 6;
  const int wr   = w >> 1;
  const int wc   = w & 1;
  const int quad = lane >> 4;
  const int lc   = lane & 15;
  const int trow = tid >> 3;                 // 0..31
  const int tg   = tid & 7;                  // granule 0..7
  const int tslot = (tg ^ (trow & 7)) * 8;

  floatx4 acc[2][2] = {};

  for (int k0 = 0; k0 < DM; k0 += 64) {
    uint4 ua[2], ub[2];
#pragma unroll
    for (int u = 0; u < 2; ++u) {
      ua[u] = *(const uint4*)&Abf[(size_t)(row0 + u * 32 + trow) * DM + k0 + tg * 8];
      ub[u] = *(const uint4*)&Bp[(size_t)(col0 + u * 32 + trow) * DM + k0 + tg * 8];
    }
    __syncthreads();   // previous iteration's LDS reads complete
#pragma unroll
    for (int u = 0; u < 2; ++u) {
      *(uint4*)&As[(u * 32 + trow) * 64 + tslot] = ua[u];
      *(uint4*)&Bs[(u * 32 + trow) * 64 + tslot] = ub[u];
    }
    __syncthreads();

#pragma unroll
    for (int s = 0; s < 2; ++s) {
      const int gk = s * 4 + quad;
      short8 aF[2], bF[2];
#pragma unroll
      for (int i = 0; i < 2; ++i) {
        const int m = wr * 32 + i * 16 + lc;
        aF[i] = *(const short8*)&As[m * 64 + (gk ^ (m & 7)) * 8];
      }
#pragma unroll
      for (int j = 0; j < 2; ++j) {
        const int n = wc * 32 + j * 16 + lc;
        bF[j] = *(const short8*)&Bs[n * 64 + (gk ^ (n & 7)) * 8];
      }
#pragma unroll
      for (int i = 0; i < 2; ++i)
#pragma unroll
        for (int j = 0; j < 2; ++j)
          acc[i][j] = __builtin_amdgcn_mfma_f32_16x16x32_bf16(
              aF[i], bF[j], acc[i][j], 0, 0, 0);
    }
  }

  // C/D layout: col = lane&15, row = quad*4 + reg  [m89/m91]
#pragma unroll
  for (int i = 0; i < 2; ++i)
#pragma unroll
    for (int j = 0; j < 2; ++j) {
      const int col = col0 + wc * 32 + j * 16 + lc;
#pragma unroll
      for (int r = 0; r < 4; ++r) {
        const int row = row0 + wr * 32 + i * 16 + quad * 4 + r;
        C[(size_t)row * DM + col] = f2bf(acc[i][j][r]);
      }
    }
}

// ---------------------------------------------------------------------------
// Output projection: out[M,N] fp32 = attn[M,K]bf16 * Wo[N,K]^T bf16.
// Same verified tile. Grid 8x32 = 256 blocks.
// ---------------------------------------------------------------------------
__global__ __launch_bounds__(256) void gemm_proj(
    const unsigned short* __restrict__ Abf,
    const unsigned short* __restrict__ Bp,
    float* __restrict__ C) {
  __shared__ unsigned short As[64 * 64];
  __shared__ unsigned short Bs[64 * 64];

  const int row0 = blockIdx.y * 64;
  const int col0 = blockIdx.x * 64;
  const int tid  = threadIdx.x;
  const int lane = tid & 63;
  const int w    = tid >> 6;
  const int wr   = w >> 1;
  const int wc   = w & 1;
  const int quad = lane >> 4;
  const int lc   = lane & 15;
  const int trow = tid >> 3;
  const int tg   = tid & 7;
  const int tslot = (tg ^ (trow & 7)) * 8;

  floatx4 acc[2][2] = {};

  for (int k0 = 0; k0 < DM; k0 += 64) {
    uint4 ua[2], ub[2];
#pragma unroll
    for (int u = 0; u < 2; ++u) {
      ua[u] = *(const uint4*)&Abf[(size_t)(row0 + u * 32 + trow) * DM + k0 + tg * 8];
      ub[u] = *(const uint4*)&Bp[(size_t)(col0 + u * 32 + trow) * DM + k0 + tg * 8];
    }
    __syncthreads();
#pragma unroll
    for (int u = 0; u < 2; ++u) {
      *(uint4*)&As[(u * 32 + trow) * 64 + tslot] = ua[u];
      *(uint4*)&Bs[(u * 32 + trow) * 64 + tslot] = ub[u];
    }
    __syncthreads();

#pragma unroll
    for (int s = 0; s < 2; ++s) {
      const int gk = s * 4 + quad;
      short8 aF[2], bF[2];
#pragma unroll
      for (int i = 0; i < 2; ++i) {
        const int m = wr * 32 + i * 16 + lc;
        aF[i] = *(const short8*)&As[m * 64 + (gk ^ (m & 7)) * 8];
      }
#pragma unroll
      for (int j = 0; j < 2; ++j) {
        const int n = wc * 32 + j * 16 + lc;
        bF[j] = *(const short8*)&Bs[n * 64 + (gk ^ (n & 7)) * 8];
      }
#pragma unroll
      for (int i = 0; i < 2; ++i)
#pragma unroll
        for (int j = 0; j < 2; ++j)
          acc[i][j] = __builtin_amdgcn_mfma_f32_16x16x32_bf16(
              aF[i], bF[j], acc[i][j], 0, 0, 0);
    }
  }

#pragma unroll
  for (int i = 0; i < 2; ++i)
#pragma unroll
    for (int j = 0; j < 2; ++j) {
      const int col = col0 + wc * 32 + j * 16 + lc;
#pragma unroll
      for (int r = 0; r < 4; ++r) {
        const int row = row0 + wr * 32 + i * 16 + quad * 4 + r;
        C[(size_t)row * DM + col] = acc[i][j][r];
      }
    }
}

// ---------------------------------------------------------------------------
// Sliding-window per-channel softmax, bf16 in/out, 8 channels per thread.
// Wave = one row (64 lanes x 8 ch = 512): trip count wave-uniform, k/v loads
// are dwordx4 -> each wave load instr covers a full contiguous 1KB row.
// Shift-invariant softmax (|s| small -> fp32 exp safe, R3+-verified).
// ---------------------------------------------------------------------------
__global__ __launch_bounds__(256) void swin_attn8(
    const unsigned short* __restrict__ qkv, unsigned short* __restrict__ o) {
  const int gid = blockIdx.x * 256 + threadIdx.x;
  const int i  = gid >> 6;             // row 0..2047 (uniform per wave)
  const int c8 = (gid & 63) * 8;       // channel octet

  const unsigned short* q = qkv;
  const unsigned short* k = qkv + (size_t)S * DM;
  const unsigned short* v = qkv + 2 * (size_t)S * DM;

  uint4 qp = *(const uint4*)&q[(size_t)i * DM + c8];
  float qs[8];
  unpack2(qp.x, qs[0], qs[1]); unpack2(qp.y, qs[2], qs[3]);
  unpack2(qp.z, qs[4], qs[5]); unpack2(qp.w, qs[6], qs[7]);
#pragma unroll
  for (int c = 0; c < 8; ++c) qs[c] *= ATTN_SCALE;

  float l[8], a[8];
#pragma unroll
  for (int c = 0; c < 8; ++c) { l[c] = 0.f; a[c] = 0.f; }

  const int j0 = i > (WIN - 1) ? i - (WIN - 1) : 0;
  for (int j = j0; j <= i; ++j) {
    uint4 kp = *(const uint4*)&k[(size_t)j * DM + c8];
    uint4 vp = *(const uint4*)&v[(size_t)j * DM + c8];
    float kf[8], vf[8];
    unpack2(kp.x, kf[0], kf[1]); unpack2(kp.y, kf[2], kf[3]);
    unpack2(kp.z, kf[4], kf[5]); unpack2(kp.w, kf[6], kf[7]);
    unpack2(vp.x, vf[0], vf[1]); unpack2(vp.y, vf[2], vf[3]);
    unpack2(vp.z, vf[4], vf[5]); unpack2(vp.w, vf[6], vf[7]);
#pragma unroll
    for (int c = 0; c < 8; ++c) {
      const float p = __expf(qs[c] * kf[c]);
      l[c] += p;
      a[c] = fmaf(p, vf[c], a[c]);
    }
  }

  uint4 ov;
  ov.x = pack_bf16_rh(a[0] / l[0], a[1] / l[1]);
  ov.y = pack_bf16_rh(a[2] / l[2], a[3] / l[3]);
  ov.z = pack_bf16_rh(a[4] / l[4], a[5] / l[5]);
  ov.w = pack_bf16_rh(a[6] / l[6], a[7] / l[7]);
  *(uint4*)&o[(size_t)i * DM + c8] = ov;
}

// ---------------------------------------------------------------------------
// Launch: 4 dispatches (convert, qkv, attn, proj).
// ---------------------------------------------------------------------------
extern "C" void kernel_launch(void* const* d_in, const int* in_sizes, int n_in,
                              void* d_out, int out_size, void* d_ws, size_t ws_size,
                              hipStream_t stream) {
  const float* x  = (const float*)d_in[0];
  const float* Wq = (const float*)d_in[1];
  const float* Wk = (const float*)d_in[2];
  const float* Wv = (const float*)d_in[3];
  const float* Wo = (const float*)d_in[4];
  float* out = (float*)d_out;

  // ws: xbf 2MB | wbf 2MB | qkvb 6MB | attnb 2MB  (12 MB)
  unsigned short* xbf   = (unsigned short*)d_ws;
  unsigned short* wbf   = xbf + (size_t)S * DM;
  unsigned short* qkvb  = wbf + 4 * (size_t)DM * DM;
  unsigned short* attnb = qkvb + 3 * (size_t)S * DM;

  // 1) fp32 -> bf16 (x and all four W)
  convert_bf16<<<dim3(2048), dim3(256), 0, stream>>>(x, Wq, Wk, Wv, Wo, xbf, wbf);

  // 2) fused QKV GEMM -> bf16 q|k|v  (768 blocks = 3/CU)
  gemm_qkv<<<dim3(DM / 64, S / 64, 3), dim3(256), 0, stream>>>(xbf, wbf, qkvb);

  // 3) sliding-window per-channel softmax (512 blocks, wave-per-row)
  swin_attn8<<<dim3(S * 64 / 256), dim3(256), 0, stream>>>(qkvb, attnb);

  // 4) output projection (256 blocks)
  gemm_proj<<<dim3(DM / 64, S / 64), dim3(256), 0, stream>>>(
      attnb, wbf + 3 * (size_t)DM * DM, out);
}